// Round 3
// baseline (4938.690 us; speedup 1.0000x reference)
//
#include <hip/hip_runtime.h>

#define BATCH    64
#define TSTEPS   2048
#define DIN      64
#define UNITS    128
#define UNFOLDS  6
#define NTHREADS 512
#define CHS      12   // LDS words per 8-float h chunk (8 data + 4 pad)

// Thread (g = tid>>4, p = tid&15) owns units {4g..4g+3}, K-chunk [8p,8p+8).
// One 8-float h read feeds 32 FMAs (4x reuse) -> 16 ds_read_b128/CU/sub-step
// instead of 64. 16-way K-reduce entirely on VALU via DPP (quad_perm +
// row_ror), no LDS. h chunk p at word 12p: banks 12p%32 pair up (p,p+8) ->
// 2-way aliasing = free. Owners (p==0) publish h; their lanes alone feed the
// fused output head, so replica ULP drift on p!=0 lanes is harmless.

template <int CTRL>
__device__ __forceinline__ float dpp_f(float v) {
    return __int_as_float(
        __builtin_amdgcn_mov_dpp(__float_as_int(v), CTRL, 0xF, 0xF, true));
}

__device__ __forceinline__ float rowsum16(float v) {
    v += dpp_f<0xB1>(v);   // quad_perm [1,0,3,2]  : xor 1
    v += dpp_f<0x4E>(v);   // quad_perm [2,3,0,1]  : xor 2
    v += dpp_f<0x124>(v);  // row_ror:4            : + quad c+1
    v += dpp_f<0x128>(v);  // row_ror:8            : + quads c+2,c+3
    return v;              // all 16 row lanes hold the row total
}

__global__ __launch_bounds__(NTHREADS) void ltc_fused_kernel(
    const float* __restrict__ x,      // [B,T,DIN]
    const float* __restrict__ kern,   // [DIN,UNITS]
    const float* __restrict__ rk,     // [UNITS,UNITS]
    const float* __restrict__ bias,   // [UNITS]
    const float* __restrict__ tau,    // [UNITS]
    const float* __restrict__ Avec,   // [UNITS]
    const float* __restrict__ okern,  // [UNITS,1]
    const float* __restrict__ obias,  // [1]
    float* __restrict__ out)          // [B,T,1]
{
    const int b    = blockIdx.x;
    const int tid  = threadIdx.x;
    const int p    = tid & 15;   // K-chunk id
    const int g    = tid >> 4;   // unit group (units 4g..4g+3)
    const int wid  = tid >> 6;
    const int lane = tid & 63;

    __shared__ __align__(16) float hbuf[2][16 * CHS];
    __shared__ float part[8];

    // ---- resident weights: rk[8p+m][4g+i] and kern[4p+m][4g+i] ----
    float w_[8][4];
    #pragma unroll
    for (int m = 0; m < 8; ++m) {
        float4 v = ((const float4*)(rk + (size_t)(8 * p + m) * UNITS))[g];
        w_[m][0] = v.x; w_[m][1] = v.y; w_[m][2] = v.z; w_[m][3] = v.w;
    }
    float kk_[4][4];
    #pragma unroll
    for (int m = 0; m < 4; ++m) {
        float4 v = ((const float4*)(kern + (size_t)(4 * p + m) * UNITS))[g];
        kk_[m][0] = v.x; kk_[m][1] = v.y; kk_[m][2] = v.z; kk_[m][3] = v.w;
    }

    const float dt = 1.0f / 6.0f;
    float4 a4  = ((const float4*)Avec)[g];
    float4 t4  = ((const float4*)tau)[g];
    float4 o4  = ((const float4*)okern)[g];
    float4 b4  = ((const float4*)bias)[g];

    float dtA_[4]  = {dt * a4.x, dt * a4.y, dt * a4.z, dt * a4.w};
    float cden_[4] = {1.0f + dt / t4.x, 1.0f + dt / t4.y,
                      1.0f + dt / t4.z, 1.0f + dt / t4.w};
    float cdp_[4]  = {cden_[0] + dt, cden_[1] + dt, cden_[2] + dt, cden_[3] + dt};
    float okf_[4]  = {o4.x, o4.y, o4.z, o4.w};
    float bf_[4]   = {b4.x, b4.y, b4.z, b4.w};
    const float ob = obias[0];

    float hu[4] = {0.0f, 0.0f, 0.0f, 0.0f};
    if (tid < 16 * CHS) hbuf[0][tid] = 0.0f;

    const float* xb = x + (size_t)b * TSTEPS * DIN;
    float4 xr = ((const float4*)xb)[p];   // x[t=0][4p..4p+4)
    __syncthreads();

    for (int t = 0; t < TSTEPS; ++t) {
        // input-projection partial for this (g,p): valid all 6 sub-steps
        float xp[4];
        #pragma unroll
        for (int i = 0; i < 4; ++i) xp[i] = (p == 0) ? bf_[i] : 0.0f;
        {
            float xrf[4] = {xr.x, xr.y, xr.z, xr.w};
            #pragma unroll
            for (int m = 0; m < 4; ++m)
                #pragma unroll
                for (int i = 0; i < 4; ++i)
                    xp[i] = fmaf(xrf[m], kk_[m][i], xp[i]);
        }

        // prefetch next x row (raw s_barrier: no vmcnt drain -> stays hidden)
        int tn = (t + 1 < TSTEPS) ? t + 1 : t;
        float4 xn = ((const float4*)(xb + (size_t)tn * DIN))[p];

        #pragma unroll
        for (int s = 0; s < UNFOLDS; ++s) {
            const float4* hv = (const float4*)&hbuf[s & 1][CHS * p];
            float4 ha = hv[0], hb = hv[1];
            float hf[8] = {ha.x, ha.y, ha.z, ha.w, hb.x, hb.y, hb.z, hb.w};

            float acc[4];
            #pragma unroll
            for (int i = 0; i < 4; ++i) acc[i] = xp[i];
            #pragma unroll
            for (int m = 0; m < 8; ++m)
                #pragma unroll
                for (int i = 0; i < 4; ++i)
                    acc[i] = fmaf(hf[m], w_[m][i], acc[i]);

            // 16-way K-reduce on VALU (DPP), then gating + update
            #pragma unroll
            for (int i = 0; i < 4; ++i) {
                float tot = rowsum16(acc[i]);
                tot = fminf(fmaxf(tot, -30.0f), 30.0f);
                float e   = __expf(-tot);          // f = 1/(1+e)
                float s0  = hu[i] + dtA_[i];
                float num = fmaf(hu[i], e, s0);    // (h + dt f A)(1+e)
                float den = fmaf(cden_[i], e, cdp_[i]); // (1+dt(itau+f))(1+e)
                hu[i] = num * __builtin_amdgcn_rcpf(den);
            }

            if (p == 0) {
                // units 4g..4g+3 -> chunk g>>1, offset 4*(g&1)
                float4 st; st.x = hu[0]; st.y = hu[1]; st.z = hu[2]; st.w = hu[3];
                *(float4*)&hbuf[(s & 1) ^ 1][CHS * (g >> 1) + 4 * (g & 1)] = st;
            }

            if (s == UNFOLDS - 1) {
                // fused head: only p==0 columns (lanes 0,16,32,48) feed lane 0
                float q = 0.0f;
                #pragma unroll
                for (int i = 0; i < 4; ++i) q = fmaf(hu[i], okf_[i], q);
                q += __shfl_xor(q, 16);
                q += __shfl_xor(q, 32);
                if (lane == 0) part[wid] = q;
            }

            asm volatile("s_waitcnt lgkmcnt(0)" ::: "memory");
            __builtin_amdgcn_sched_barrier(0);
            __builtin_amdgcn_s_barrier();
            __builtin_amdgcn_sched_barrier(0);
        }

        if (tid == 0) {
            float r = ob;
            #pragma unroll
            for (int k = 0; k < 8; ++k) r += part[k];
            out[(size_t)b * TSTEPS + t] = r;
        }
        xr = xn;
    }
}

extern "C" void kernel_launch(void* const* d_in, const int* in_sizes, int n_in,
                              void* d_out, int out_size, void* d_ws, size_t ws_size,
                              hipStream_t stream) {
    const float* x     = (const float*)d_in[0];
    const float* kern  = (const float*)d_in[1];
    const float* rk    = (const float*)d_in[2];
    const float* bias  = (const float*)d_in[3];
    const float* tau   = (const float*)d_in[4];
    const float* Avec  = (const float*)d_in[5];
    const float* okern = (const float*)d_in[6];
    const float* obias = (const float*)d_in[7];
    float* out = (float*)d_out;

    ltc_fused_kernel<<<BATCH, NTHREADS, 0, stream>>>(
        x, kern, rk, bias, tau, Avec, okern, obias, out);
}

// Round 6
// 3818.366 us; speedup vs baseline: 1.2934x; 1.2934x over previous
//
#include <hip/hip_runtime.h>

#define TSTEPS  2048
#define DIN     64
#define UNITS   128
#define UNFOLDS 6
#define NT      512
#define CSTR    20   // floats per 8-float h chunk (8 data + 12 pad); 80 B, 16B-aligned

// Thread (g = tid>>4, p = tid&15) owns units {4g..4g+3} x K-chunk [8p,8p+8).
// 32 FMAs/thread; h read as 2x ds_read_b128 (16 distinct addrs/wave, 4-lane
// broadcast, 2-way bank alias = free). K-reduce is a 16-lane REDUCE-SCATTER
// (6 cndmask + 5 dpp-adds): lane p ends owning unit 4g+sel(p&3)'s total ->
// nonlinearity computed ONCE per lane (R2's 16x replication removed), h
// carried in one register. p<4 lanes publish h (conflict-free b32). x row
// loaded per-thread float4 from global, prefetched one t ahead (raw
// s_barrier: no vmcnt drain). Head: p<4 lanes' h*ok, full-wave xor-reduce.

template <int CTRL>
__device__ __forceinline__ float dpp_f(float v) {
    return __int_as_float(
        __builtin_amdgcn_mov_dpp(__float_as_int(v), CTRL, 0xF, 0xF, true));
}

__global__ __launch_bounds__(NT) void ltc_kernel(
    const float* __restrict__ x,      // [B,T,DIN]
    const float* __restrict__ kern,   // [DIN,UNITS]
    const float* __restrict__ rk,     // [UNITS,UNITS]
    const float* __restrict__ bias,   // [UNITS]
    const float* __restrict__ tau,    // [UNITS]
    const float* __restrict__ Avec,   // [UNITS]
    const float* __restrict__ okern,  // [UNITS,1]
    const float* __restrict__ obias,  // [1]
    float* __restrict__ out)          // [B,T,1]
{
    const int b    = blockIdx.x;
    const int tid  = threadIdx.x;
    const int p    = tid & 15;
    const int g    = tid >> 4;      // unit group: units 4g..4g+3
    const int wid  = tid >> 6;
    const int lane = tid & 63;

    __shared__ __align__(16) float hbuf[2][16 * CSTR];
    __shared__ float part[8];

    // resident weights: rk[8p+m][4g+i], kern[4p+m][4g+i]
    float w_[8][4];
    #pragma unroll
    for (int m = 0; m < 8; ++m) {
        float4 v = ((const float4*)(rk + (size_t)(8 * p + m) * UNITS))[g];
        w_[m][0] = v.x; w_[m][1] = v.y; w_[m][2] = v.z; w_[m][3] = v.w;
    }
    float kk_[4][4];
    #pragma unroll
    for (int m = 0; m < 4; ++m) {
        float4 v = ((const float4*)(kern + (size_t)(4 * p + m) * UNITS))[g];
        kk_[m][0] = v.x; kk_[m][1] = v.y; kk_[m][2] = v.z; kk_[m][3] = v.w;
    }

    const float dt  = 1.0f / 6.0f;
    const int   sel = ((p & 1) << 1) | ((p >> 1) & 1);  // scatter endpoint
    const int   u_own = 4 * g + sel;
    const float dtA_o  = dt * Avec[u_own];
    const float cden_o = 1.0f + dt / tau[u_own];
    const float cdp_o  = cden_o + dt;
    const float ok_o   = okern[u_own];
    float4 bv = ((const float4*)bias)[g];
    float bias4[4] = {bv.x, bv.y, bv.z, bv.w};
    const float ob = obias[0];

    const int waddr = CSTR * (u_own >> 3) + (u_own & 7);

    float h_own = 0.0f;
    if (tid < 16 * CSTR) hbuf[0][tid] = 0.0f;

    const float* xb = x + (size_t)b * TSTEPS * DIN;
    float4 xr = *(const float4*)(xb + 4 * p);   // x[b][0][4p..4p+4)
    __syncthreads();

    for (int t = 0; t < TSTEPS; ++t) {
        // input-projection partial (this lane's 4-din chunk), all 6 sub-steps
        float xp[4];
        #pragma unroll
        for (int i = 0; i < 4; ++i) xp[i] = (p == 0) ? bias4[i] : 0.0f;
        {
            float xrf[4] = {xr.x, xr.y, xr.z, xr.w};
            #pragma unroll
            for (int m = 0; m < 4; ++m)
                #pragma unroll
                for (int i = 0; i < 4; ++i)
                    xp[i] = fmaf(xrf[m], kk_[m][i], xp[i]);
        }
        // prefetch next x row (stays in flight across raw barriers)
        int tn = (t + 1 < TSTEPS) ? t + 1 : t;
        float4 xn = *(const float4*)(xb + (size_t)tn * DIN + 4 * p);

        #pragma unroll
        for (int s = 0; s < UNFOLDS; ++s) {
            const float4* hv = (const float4*)&hbuf[s & 1][CSTR * p];
            float4 h0 = hv[0], h1 = hv[1];
            float hf[8] = {h0.x, h0.y, h0.z, h0.w, h1.x, h1.y, h1.z, h1.w};

            float acc[4] = {xp[0], xp[1], xp[2], xp[3]};
            #pragma unroll
            for (int m = 0; m < 8; ++m)
                #pragma unroll
                for (int i = 0; i < 4; ++i)
                    acc[i] = fmaf(hf[m], w_[m][i], acc[i]);

            // ---- 16-lane reduce-scatter ----
            const bool b0 = (p & 1) != 0;
            const bool b1 = (p & 2) != 0;
            // xor1: even lanes keep units {0,1}, odd keep {2,3}
            float a0 = b0 ? acc[2] : acc[0];
            float c0 = b0 ? acc[0] : acc[2];
            float r0 = a0 + dpp_f<0xB1>(c0);
            float a1 = b0 ? acc[3] : acc[1];
            float c1 = b0 ? acc[1] : acc[3];
            float r1 = a1 + dpp_f<0xB1>(c1);
            // xor2: bit1=0 keeps r0, bit1=1 keeps r1
            float a2 = b1 ? r1 : r0;
            float c2 = b1 ? r0 : r1;
            float sv = a2 + dpp_f<0x4E>(c2);
            // sum the 4 quads (sel invariant under p±4)
            sv += dpp_f<0x124>(sv);   // row_ror:4
            sv += dpp_f<0x128>(sv);   // row_ror:8

            // gating + semi-implicit Euler update, once per lane
            float e   = __expf(-sv);                  // f = 1/(1+e)
            float num = fmaf(h_own, e, h_own + dtA_o);
            float den = fmaf(cden_o, e, cdp_o);
            h_own = num * __builtin_amdgcn_rcpf(den);

            if (p < 4) hbuf[(s & 1) ^ 1][waddr] = h_own;  // publish (quad 0)

            if (s == UNFOLDS - 1) {
                float q = (p < 4) ? h_own * ok_o : 0.0f;
                q += __shfl_xor(q, 1);
                q += __shfl_xor(q, 2);
                q += __shfl_xor(q, 4);
                q += __shfl_xor(q, 8);
                q += __shfl_xor(q, 16);
                q += __shfl_xor(q, 32);
                if (lane == 0) part[wid] = q;
            }

            asm volatile("s_waitcnt lgkmcnt(0)" ::: "memory");
            __builtin_amdgcn_sched_barrier(0);
            __builtin_amdgcn_s_barrier();
            __builtin_amdgcn_sched_barrier(0);
        }

        if (tid == 0) {
            float r = ob;
            #pragma unroll
            for (int k = 0; k < 8; ++k) r += part[k];
            out[(size_t)b * TSTEPS + t] = r;
        }
        xr = xn;
    }
}

extern "C" void kernel_launch(void* const* d_in, const int* in_sizes, int n_in,
                              void* d_out, int out_size, void* d_ws, size_t ws_size,
                              hipStream_t stream) {
    const float* x     = (const float*)d_in[0];
    const float* kern  = (const float*)d_in[1];
    const float* rk    = (const float*)d_in[2];
    const float* bias  = (const float*)d_in[3];
    const float* tau   = (const float*)d_in[4];
    const float* Avec  = (const float*)d_in[5];
    const float* okern = (const float*)d_in[6];
    const float* obias = (const float*)d_in[7];
    float* out = (float*)d_out;

    ltc_kernel<<<64, NT, 0, stream>>>(
        x, kern, rk, bias, tau, Avec, okern, obias, out);
}